// Round 6
// baseline (762.964 us; speedup 1.0000x reference)
//
#include <hip/hip_runtime.h>
#include <cstdint>
#include <cstddef>

#define N_NODES 10000
#define N_EDGES 160000
#define DIM_IN  512
#define HIDDIM  128
#define NHEAD   8
#define NLAYER  4

static __device__ __forceinline__ float eluf(float v)  { return v > 0.f ? v : expm1f(v); }
static __device__ __forceinline__ float lrelu(float v) { return v >= 0.f ? v : 0.2f * v; }

#define BN_INV 0.9999950000374997f  /* 1/sqrt(1+1e-5) */

// ---------------------------------------------------------------------------
// CSR build: degree histogram -> block scan -> scatter (src per incoming edge)
// edge_index arrives as int32 (harness converts integer inputs to int32).
// ---------------------------------------------------------------------------
__global__ void k_deg(const int* __restrict__ ei, int* __restrict__ deg) {
    int t = blockIdx.x * 256 + threadIdx.x;
    if (t < N_EDGES) atomicAdd(&deg[ei[N_EDGES + t]], 1);
}

__global__ __launch_bounds__(1024) void k_scan(const int* __restrict__ deg,
                                               int* __restrict__ rowptr,
                                               int* __restrict__ cursor) {
    __shared__ int sd[1024];
    __shared__ int carry;
    int tid = threadIdx.x;
    if (tid == 0) { carry = 0; rowptr[0] = 0; }
    __syncthreads();
    for (int base = 0; base < N_NODES; base += 1024) {
        int i = base + tid;
        int v = (i < N_NODES) ? (deg[i] + 1) : 0;  // +1 = self loop
        sd[tid] = v;
        __syncthreads();
        for (int ofs = 1; ofs < 1024; ofs <<= 1) {
            int t = (tid >= ofs) ? sd[tid - ofs] : 0;
            __syncthreads();
            sd[tid] += t;
            __syncthreads();
        }
        int inc = sd[tid] + carry;
        if (i < N_NODES) { rowptr[i + 1] = inc; cursor[i] = inc - v; }
        __syncthreads();
        if (tid == 1023) carry = inc;
        __syncthreads();
    }
}

__global__ void k_scatter(const int* __restrict__ ei, int* __restrict__ cursor,
                          int* __restrict__ csr) {
    int t = blockIdx.x * 256 + threadIdx.x;
    if (t < N_EDGES) {
        int s = ei[t];
        int d = ei[N_EDGES + t];
        int p = atomicAdd(&cursor[d], 1);
        csr[p] = s;
    } else if (t < N_EDGES + N_NODES) {
        int n = t - N_EDGES;
        int p = atomicAdd(&cursor[n], 1);
        csr[p] = n;  // self loop
    }
}

// ---------------------------------------------------------------------------
// fp32 tiled GEMM: C[M,Nn] = A[M,K] @ B[K,Nn]; ACT=1 -> elu(.+bias)
// BM=BN=64, BK=16, 256 threads, 4x4 microtile
// ---------------------------------------------------------------------------
template <int ACT>
__global__ __launch_bounds__(256) void k_gemm(const float* __restrict__ A,
                                              const float* __restrict__ B,
                                              const float* __restrict__ bias,
                                              float* __restrict__ C,
                                              int M, int Nn, int K) {
    __shared__ float As[16][64];
    __shared__ float Bs[16][64];
    const int tx = threadIdx.x & 15;
    const int ty = threadIdx.x >> 4;
    const int row0 = blockIdx.y * 64, col0 = blockIdx.x * 64;
    const int la_m = threadIdx.x >> 2;
    const int la_k = (threadIdx.x & 3) * 4;
    const int lb_k = threadIdx.x >> 4;
    const int lb_n = (threadIdx.x & 15) * 4;
    float acc[4][4] = {};
    for (int k0 = 0; k0 < K; k0 += 16) {
        float4 av = make_float4(0.f, 0.f, 0.f, 0.f);
        int ar = row0 + la_m;
        if (ar < M) av = *(const float4*)(A + (size_t)ar * K + k0 + la_k);
        As[la_k + 0][la_m] = av.x;
        As[la_k + 1][la_m] = av.y;
        As[la_k + 2][la_m] = av.z;
        As[la_k + 3][la_m] = av.w;
        *(float4*)&Bs[lb_k][lb_n] = *(const float4*)(B + (size_t)(k0 + lb_k) * Nn + col0 + lb_n);
        __syncthreads();
#pragma unroll
        for (int k = 0; k < 16; k++) {
            float a[4], b[4];
#pragma unroll
            for (int i = 0; i < 4; i++) a[i] = As[k][ty * 4 + i];
#pragma unroll
            for (int j = 0; j < 4; j++) b[j] = Bs[k][tx * 4 + j];
#pragma unroll
            for (int i = 0; i < 4; i++)
#pragma unroll
                for (int j = 0; j < 4; j++) acc[i][j] += a[i] * b[j];
        }
        __syncthreads();
    }
#pragma unroll
    for (int i = 0; i < 4; i++) {
        int r = row0 + ty * 4 + i;
        if (r < M) {
            float4 o;
            float* op = (float*)&o;
#pragma unroll
            for (int j = 0; j < 4; j++) {
                float v = acc[i][j];
                if (ACT) {
                    v += bias[col0 + tx * 4 + j];
                    v = eluf(v);
                }
                op[j] = v;
            }
            *(float4*)(C + (size_t)r * Nn + col0 + tx * 4) = o;
        }
    }
}

// ---------------------------------------------------------------------------
// alpha_s[n,h] = sum_c xl[n,h,c]*att_src[h,c];  alpha_d analogous.
// One wave per node; lane i holds float4 at flat=256j+4i; head = 2j + (i>>5).
// ---------------------------------------------------------------------------
__global__ __launch_bounds__(256) void k_alphas(const float* __restrict__ xl,
                                                const float* __restrict__ atts,
                                                const float* __restrict__ attd,
                                                float* __restrict__ as_,
                                                float* __restrict__ ad_) {
    int lane = threadIdx.x & 63;
    int n = blockIdx.x * 4 + (threadIdx.x >> 6);
    if (n >= N_NODES) return;
    int hi = lane >> 5;
    int c0 = (4 * lane) & 127;
    const float4* xp = (const float4*)(xl + (size_t)n * 1024);
    float ss[4], sd[4];
#pragma unroll
    for (int j = 0; j < 4; j++) {
        int head = 2 * j + hi;
        float4 v = xp[j * 64 + lane];
        float4 a = *(const float4*)(atts + head * 128 + c0);
        float4 b = *(const float4*)(attd + head * 128 + c0);
        ss[j] = v.x * a.x + v.y * a.y + v.z * a.z + v.w * a.w;
        sd[j] = v.x * b.x + v.y * b.y + v.z * b.z + v.w * b.w;
    }
#pragma unroll
    for (int m = 1; m < 32; m <<= 1) {
#pragma unroll
        for (int j = 0; j < 4; j++) {
            ss[j] += __shfl_xor(ss[j], m);
            sd[j] += __shfl_xor(sd[j], m);
        }
    }
    if ((lane & 31) == 0) {
#pragma unroll
        for (int j = 0; j < 4; j++) {
            as_[n * 8 + 2 * j + hi] = ss[j];
            ad_[n * 8 + 2 * j + hi] = sd[j];
        }
    }
}

// ---------------------------------------------------------------------------
// Per-dst aggregation + mean-over-heads + bias + BN + residual + ELU.
// One wave per node. Pass1: per-head max. Pass2: acc = sum ee*xl[src], denom.
// ---------------------------------------------------------------------------
__global__ __launch_bounds__(256) void k_aggregate(const int* __restrict__ rowptr,
                                                   const int* __restrict__ csr,
                                                   const float* __restrict__ as_,
                                                   const float* __restrict__ ad_,
                                                   const float* __restrict__ xl,
                                                   const float* __restrict__ hprev,
                                                   const float* __restrict__ bl,
                                                   const float* __restrict__ gam,
                                                   const float* __restrict__ bet,
                                                   float* __restrict__ hnext) {
    int lane = threadIdx.x & 63;
    int n = blockIdx.x * 4 + (threadIdx.x >> 6);
    if (n >= N_NODES) return;
    int hi = lane >> 5;
    int h8 = lane & 7;
    float ad = (lane < 8) ? ad_[n * 8 + lane] : 0.f;
    float adh = __shfl(ad, h8);  // alpha_dst for head h8, all lanes
    int start = rowptr[n], end = rowptr[n + 1];

    // pass 1: per-head max over incoming edges (8 edges x 8 heads per step)
    float mx = -1e30f;
    for (int e0 = start; e0 < end; e0 += 8) {
        int eidx = e0 + (lane >> 3);
        float v = -1e30f;
        if (eidx < end) {
            int s = csr[eidx];
            v = lrelu(as_[s * 8 + h8] + adh);
        }
        mx = fmaxf(mx, v);
    }
    mx = fmaxf(mx, __shfl_xor(mx, 8));
    mx = fmaxf(mx, __shfl_xor(mx, 16));
    mx = fmaxf(mx, __shfl_xor(mx, 32));  // mx valid for head=lane&7 in every lane

    // pass 2: accumulate
    float4 acc[4];
#pragma unroll
    for (int j = 0; j < 4; j++) acc[j] = make_float4(0.f, 0.f, 0.f, 0.f);
    float denom = 0.f;
    for (int eidx = start; eidx < end; ++eidx) {
        int s = csr[eidx];
        float t = lrelu(as_[s * 8 + h8] + adh);
        float ee = __expf(t - mx);
        denom += ee;  // lanes 0..7 hold the per-head denominators
        const float4* xp = (const float4*)(xl + (size_t)s * 1024);
#pragma unroll
        for (int j = 0; j < 4; j++) {
            float eej = __shfl(ee, 2 * j + hi);
            float4 v = xp[j * 64 + lane];
            acc[j].x += eej * v.x;
            acc[j].y += eej * v.y;
            acc[j].z += eej * v.z;
            acc[j].w += eej * v.w;
        }
    }

    // combine heads: sum_j acc[j]/denom[2j+hi], then fold lane^32 (other 4 heads)
    float4 sum = make_float4(0.f, 0.f, 0.f, 0.f);
#pragma unroll
    for (int j = 0; j < 4; j++) {
        float dj = __shfl(denom, 2 * j + hi);
        float rj = 1.f / (dj + 1e-16f);
        sum.x += acc[j].x * rj;
        sum.y += acc[j].y * rj;
        sum.z += acc[j].z * rj;
        sum.w += acc[j].w * rj;
    }
    sum.x += __shfl_xor(sum.x, 32);
    sum.y += __shfl_xor(sum.y, 32);
    sum.z += __shfl_xor(sum.z, 32);
    sum.w += __shfl_xor(sum.w, 32);

    if (lane < 32) {
        int c = 4 * lane;
        float4 bb = *(const float4*)(bl + c);
        float4 gg = *(const float4*)(gam + c);
        float4 be = *(const float4*)(bet + c);
        float4 pv = *(const float4*)(hprev + (size_t)n * 128 + c);
        float4 o;
        float* sp = (float*)&sum;
        float* bbp = (float*)&bb;
        float* ggp = (float*)&gg;
        float* bep = (float*)&be;
        float* pvp = (float*)&pv;
        float* op = (float*)&o;
#pragma unroll
        for (int t = 0; t < 4; t++) {
            float m = sp[t] * 0.125f + bbp[t];          // mean over heads + bias
            float g = ggp[t] * (m * BN_INV) + bep[t];   // BN eval
            float z = 0.9f * g + 0.1f * pvp[t];         // residual
            op[t] = eluf(z);
        }
        *(float4*)(hnext + (size_t)n * 128 + c) = o;
    }
}

// ---------------------------------------------------------------------------
// Classifier head: out = elu(h@W1+b1) @ W2 + b2, one wave per node.
// ---------------------------------------------------------------------------
__global__ __launch_bounds__(256) void k_classifier(const float* __restrict__ h,
                                                    const float* __restrict__ W1,
                                                    const float* __restrict__ b1,
                                                    const float* __restrict__ W2,
                                                    const float* __restrict__ b2,
                                                    float* __restrict__ out) {
    __shared__ float sW1[128 * 64];
    __shared__ float sW2[128];
    __shared__ float sb1[64];
    __shared__ float sb2[2];
    for (int i = threadIdx.x; i < 2048; i += 256)
        *(float4*)&sW1[i * 4] = *(const float4*)(W1 + i * 4);
    if (threadIdx.x < 64) sb1[threadIdx.x] = b1[threadIdx.x];
    if (threadIdx.x < 128) sW2[threadIdx.x] = W2[threadIdx.x];
    if (threadIdx.x < 2) sb2[threadIdx.x] = b2[threadIdx.x];
    __syncthreads();
    int lane = threadIdx.x & 63;
    int n = blockIdx.x * 4 + (threadIdx.x >> 6);
    if (n >= N_NODES) return;
    float h0 = h[(size_t)n * 128 + lane];
    float h1 = h[(size_t)n * 128 + 64 + lane];
    float acc = sb1[lane];
#pragma unroll
    for (int c = 0; c < 64; c++) acc += __shfl(h0, c) * sW1[c * 64 + lane];
#pragma unroll
    for (int c = 0; c < 64; c++) acc += __shfl(h1, c) * sW1[(64 + c) * 64 + lane];
    acc = eluf(acc);
    float p0 = acc * sW2[lane * 2 + 0];
    float p1 = acc * sW2[lane * 2 + 1];
#pragma unroll
    for (int m = 1; m < 64; m <<= 1) {
        p0 += __shfl_xor(p0, m);
        p1 += __shfl_xor(p1, m);
    }
    if (lane == 0) {
        out[(size_t)n * 2 + 0] = p0 + sb2[0];
        out[(size_t)n * 2 + 1] = p1 + sb2[1];
    }
}

// ---------------------------------------------------------------------------
extern "C" void kernel_launch(void* const* d_in, const int* in_sizes, int n_in,
                              void* d_out, int out_size, void* d_ws, size_t ws_size,
                              hipStream_t stream) {
    const float* x       = (const float*)d_in[0];
    const int* ei        = (const int*)d_in[1];   // int32 per harness convention
    const float* Wp      = (const float*)d_in[2];
    const float* bp      = (const float*)d_in[3];
    const float* Wl      = (const float*)d_in[4];
    const float* atts    = (const float*)d_in[5];
    const float* attd    = (const float*)d_in[6];
    const float* bl      = (const float*)d_in[7];
    const float* gam     = (const float*)d_in[8];
    const float* bet     = (const float*)d_in[9];
    const float* W1      = (const float*)d_in[10];
    const float* b1      = (const float*)d_in[11];
    const float* W2      = (const float*)d_in[12];
    const float* b2      = (const float*)d_in[13];
    float* out = (float*)d_out;

    char* w = (char*)d_ws;
    auto carve = [&](size_t bytes) -> void* {
        void* p = (void*)w;
        w += (bytes + 255) & ~(size_t)255;
        return p;
    };
    int* deg     = (int*)carve((size_t)N_NODES * 4);
    int* rowptr  = (int*)carve((size_t)(N_NODES + 1) * 4);
    int* cursor  = (int*)carve((size_t)N_NODES * 4);
    int* csr     = (int*)carve((size_t)(N_EDGES + N_NODES) * 4);
    float* as_   = (float*)carve((size_t)N_NODES * 8 * 4);
    float* ad_   = (float*)carve((size_t)N_NODES * 8 * 4);
    float* xl    = (float*)carve((size_t)N_NODES * 1024 * 4);
    float* hA    = (float*)carve((size_t)N_NODES * 128 * 4);
    float* hB    = (float*)carve((size_t)N_NODES * 128 * 4);

    hipMemsetAsync(deg, 0, (size_t)N_NODES * 4, stream);
    k_deg<<<(N_EDGES + 255) / 256, 256, 0, stream>>>(ei, deg);
    k_scan<<<1, 1024, 0, stream>>>(deg, rowptr, cursor);
    k_scatter<<<(N_EDGES + N_NODES + 255) / 256, 256, 0, stream>>>(ei, cursor, csr);

    // h = elu(x @ Wp + bp)
    k_gemm<1><<<dim3(2, 157), 256, 0, stream>>>(x, Wp, bp, hA, N_NODES, 128, 512);

    float* hc = hA;
    float* hn = hB;
    for (int l = 0; l < NLAYER; l++) {
        k_gemm<0><<<dim3(16, 157), 256, 0, stream>>>(hc, Wl + (size_t)l * 128 * 1024, nullptr, xl,
                                                     N_NODES, 1024, 128);
        k_alphas<<<2500, 256, 0, stream>>>(xl, atts + l * 1024, attd + l * 1024, as_, ad_);
        k_aggregate<<<2500, 256, 0, stream>>>(rowptr, csr, as_, ad_, xl, hc, bl + l * 128,
                                              gam + l * 128, bet + l * 128, hn);
        float* tmp = hc; hc = hn; hn = tmp;
    }
    k_classifier<<<2500, 256, 0, stream>>>(hc, W1, b1, W2, b2, out);
}

// Round 7
// 585.076 us; speedup vs baseline: 1.3040x; 1.3040x over previous
//
#include <hip/hip_runtime.h>
#include <cstdint>
#include <cstddef>

#define N_NODES 10000
#define N_EDGES 160000
#define DIM_IN  512
#define HIDDIM  128
#define NHEAD   8
#define NLAYER  4

typedef unsigned int  uint32;
typedef unsigned short ushort16;

static __device__ __forceinline__ float eluf(float v)  { return v > 0.f ? v : expm1f(v); }
static __device__ __forceinline__ float lrelu(float v) { return v >= 0.f ? v : 0.2f * v; }
// round-to-nearest-even fp32 -> bf16
static __device__ __forceinline__ ushort16 f2bf(float f) {
    uint32 u = __float_as_uint(f);
    u += 0x7fffu + ((u >> 16) & 1u);
    return (ushort16)(u >> 16);
}

#define BN_INV 0.9999950000374997f  /* 1/sqrt(1+1e-5) */

// ---------------------------------------------------------------------------
// CSR build: degree histogram -> block scan -> scatter (src per incoming edge)
// edge_index arrives as int32.
// ---------------------------------------------------------------------------
__global__ void k_deg(const int* __restrict__ ei, int* __restrict__ deg) {
    int t = blockIdx.x * 256 + threadIdx.x;
    if (t < N_EDGES) atomicAdd(&deg[ei[N_EDGES + t]], 1);
}

__global__ __launch_bounds__(1024) void k_scan(const int* __restrict__ deg,
                                               int* __restrict__ rowptr,
                                               int* __restrict__ cursor) {
    __shared__ int sd[1024];
    __shared__ int carry;
    int tid = threadIdx.x;
    if (tid == 0) { carry = 0; rowptr[0] = 0; }
    __syncthreads();
    for (int base = 0; base < N_NODES; base += 1024) {
        int i = base + tid;
        int v = (i < N_NODES) ? (deg[i] + 1) : 0;  // +1 = self loop
        sd[tid] = v;
        __syncthreads();
        for (int ofs = 1; ofs < 1024; ofs <<= 1) {
            int t = (tid >= ofs) ? sd[tid - ofs] : 0;
            __syncthreads();
            sd[tid] += t;
            __syncthreads();
        }
        int inc = sd[tid] + carry;
        if (i < N_NODES) { rowptr[i + 1] = inc; cursor[i] = inc - v; }
        __syncthreads();
        if (tid == 1023) carry = inc;
        __syncthreads();
    }
}

__global__ void k_scatter(const int* __restrict__ ei, int* __restrict__ cursor,
                          int* __restrict__ csr) {
    int t = blockIdx.x * 256 + threadIdx.x;
    if (t < N_EDGES) {
        int s = ei[t];
        int d = ei[N_EDGES + t];
        int p = atomicAdd(&cursor[d], 1);
        csr[p] = s;
    } else if (t < N_EDGES + N_NODES) {
        int n = t - N_EDGES;
        int p = atomicAdd(&cursor[n], 1);
        csr[p] = n;  // self loop
    }
}

// ---------------------------------------------------------------------------
// fp32 tiled GEMM. OUTBF=0: float C, ACT=1 applies elu(.+bias).
// OUTBF=1: bf16 C (no activation). BM=BN=64, BK=16, 256 thr, 4x4 microtile.
// ---------------------------------------------------------------------------
template <int ACT, int OUTBF>
__global__ __launch_bounds__(256) void k_gemm(const float* __restrict__ A,
                                              const float* __restrict__ B,
                                              const float* __restrict__ bias,
                                              void* __restrict__ Cv,
                                              int M, int Nn, int K) {
    __shared__ float As[16][64];
    __shared__ float Bs[16][64];
    const int tx = threadIdx.x & 15;
    const int ty = threadIdx.x >> 4;
    const int row0 = blockIdx.y * 64, col0 = blockIdx.x * 64;
    const int la_m = threadIdx.x >> 2;
    const int la_k = (threadIdx.x & 3) * 4;
    const int lb_k = threadIdx.x >> 4;
    const int lb_n = (threadIdx.x & 15) * 4;
    float acc[4][4] = {};
    for (int k0 = 0; k0 < K; k0 += 16) {
        float4 av = make_float4(0.f, 0.f, 0.f, 0.f);
        int ar = row0 + la_m;
        if (ar < M) av = *(const float4*)(A + (size_t)ar * K + k0 + la_k);
        As[la_k + 0][la_m] = av.x;
        As[la_k + 1][la_m] = av.y;
        As[la_k + 2][la_m] = av.z;
        As[la_k + 3][la_m] = av.w;
        *(float4*)&Bs[lb_k][lb_n] = *(const float4*)(B + (size_t)(k0 + lb_k) * Nn + col0 + lb_n);
        __syncthreads();
#pragma unroll
        for (int k = 0; k < 16; k++) {
            float a[4], b[4];
#pragma unroll
            for (int i = 0; i < 4; i++) a[i] = As[k][ty * 4 + i];
#pragma unroll
            for (int j = 0; j < 4; j++) b[j] = Bs[k][tx * 4 + j];
#pragma unroll
            for (int i = 0; i < 4; i++)
#pragma unroll
                for (int j = 0; j < 4; j++) acc[i][j] += a[i] * b[j];
        }
        __syncthreads();
    }
#pragma unroll
    for (int i = 0; i < 4; i++) {
        int r = row0 + ty * 4 + i;
        if (r < M) {
            if (OUTBF) {
                ushort4 o;
                o.x = f2bf(acc[i][0]);
                o.y = f2bf(acc[i][1]);
                o.z = f2bf(acc[i][2]);
                o.w = f2bf(acc[i][3]);
                *(ushort4*)((ushort16*)Cv + (size_t)r * Nn + col0 + tx * 4) = o;
            } else {
                float4 o;
                float* op = (float*)&o;
#pragma unroll
                for (int j = 0; j < 4; j++) {
                    float v = acc[i][j];
                    if (ACT) {
                        v += bias[col0 + tx * 4 + j];
                        v = eluf(v);
                    }
                    op[j] = v;
                }
                *(float4*)((float*)Cv + (size_t)r * Nn + col0 + tx * 4) = o;
            }
        }
    }
}

// ---------------------------------------------------------------------------
// alpha_s[n,h] = sum_c xl[n,h,c]*att_src[h,c] (xl in bf16).
// One wave/node. Lane l, j in {0,1}: covers head 4j+(l>>4), channels
// 8*(l&15)+0..7 via one uint4 (8 bf16) load. Reduce over lane&15.
// ---------------------------------------------------------------------------
__global__ __launch_bounds__(256) void k_alphas(const ushort16* __restrict__ xl,
                                                const float* __restrict__ atts,
                                                const float* __restrict__ attd,
                                                float* __restrict__ as_,
                                                float* __restrict__ ad_) {
    int lane = threadIdx.x & 63;
    int n = blockIdx.x * 4 + (threadIdx.x >> 6);
    if (n >= N_NODES) return;
    int g = lane >> 4;          // 0..3
    int c8 = 8 * (lane & 15);   // channel base
    const uint4* xp = (const uint4*)(xl + (size_t)n * 1024);
    float ss[2], sd[2];
#pragma unroll
    for (int j = 0; j < 2; j++) {
        int head = 4 * j + g;
        uint4 u = xp[j * 64 + lane];
        const float4* ap = (const float4*)(atts + head * 128 + c8);
        const float4* bp = (const float4*)(attd + head * 128 + c8);
        float4 a0 = ap[0], a1 = ap[1];
        float4 b0 = bp[0], b1 = bp[1];
        float x0 = __uint_as_float(u.x << 16), x1 = __uint_as_float(u.x & 0xffff0000u);
        float x2 = __uint_as_float(u.y << 16), x3 = __uint_as_float(u.y & 0xffff0000u);
        float x4 = __uint_as_float(u.z << 16), x5 = __uint_as_float(u.z & 0xffff0000u);
        float x6 = __uint_as_float(u.w << 16), x7 = __uint_as_float(u.w & 0xffff0000u);
        ss[j] = x0 * a0.x + x1 * a0.y + x2 * a0.z + x3 * a0.w +
                x4 * a1.x + x5 * a1.y + x6 * a1.z + x7 * a1.w;
        sd[j] = x0 * b0.x + x1 * b0.y + x2 * b0.z + x3 * b0.w +
                x4 * b1.x + x5 * b1.y + x6 * b1.z + x7 * b1.w;
    }
#pragma unroll
    for (int m = 1; m < 16; m <<= 1) {
#pragma unroll
        for (int j = 0; j < 2; j++) {
            ss[j] += __shfl_xor(ss[j], m);
            sd[j] += __shfl_xor(sd[j], m);
        }
    }
    if ((lane & 15) == 0) {
        as_[n * 8 + g]     = ss[0];
        as_[n * 8 + 4 + g] = ss[1];
        ad_[n * 8 + g]     = sd[0];
        ad_[n * 8 + 4 + g] = sd[1];
    }
}

// ---------------------------------------------------------------------------
// Aggregation (single pass, no max-shift: |e| small so exp(e) is safe and
// exp(e)/sum exp(e) == reference's shifted ratio). bf16 xl gathers.
// One wave/node. Lane l: denom for head l&7; payload head 4j+(l>>4),
// channels 8*(l&15)+0..7. Epilogue: mean heads + bias + BN + res + ELU.
// ---------------------------------------------------------------------------
__global__ __launch_bounds__(256) void k_aggregate(const int* __restrict__ rowptr,
                                                   const int* __restrict__ csr,
                                                   const float* __restrict__ as_,
                                                   const float* __restrict__ ad_,
                                                   const ushort16* __restrict__ xl,
                                                   const float* __restrict__ hprev,
                                                   const float* __restrict__ bl,
                                                   const float* __restrict__ gam,
                                                   const float* __restrict__ bet,
                                                   float* __restrict__ hnext) {
    int lane = threadIdx.x & 63;
    int n = blockIdx.x * 4 + (threadIdx.x >> 6);
    if (n >= N_NODES) return;
    int h8 = lane & 7;
    int g = lane >> 4;
    float adh = ad_[n * 8 + h8];
    int start = rowptr[n], end = rowptr[n + 1];

    float acc0[8] = {}, acc1[8] = {};
    float denom = 0.f;
    int s = (start < end) ? csr[start] : 0;
    for (int e = start; e < end; ++e) {
        int sn = (e + 1 < end) ? csr[e + 1] : 0;  // prefetch next src idx
        float t = lrelu(as_[s * 8 + h8] + adh);
        float ee = __expf(t);
        denom += ee;                      // valid per-head in lanes 0..7 (dups above)
        float e0 = __shfl(ee, g);         // head g
        float e1 = __shfl(ee, 4 + g);     // head 4+g
        const uint4* xp = (const uint4*)(xl + (size_t)s * 1024);
        uint4 u0 = xp[lane];              // head g,   channels c8..c8+7
        uint4 u1 = xp[64 + lane];         // head 4+g, channels c8..c8+7
        acc0[0] += e0 * __uint_as_float(u0.x << 16);
        acc0[1] += e0 * __uint_as_float(u0.x & 0xffff0000u);
        acc0[2] += e0 * __uint_as_float(u0.y << 16);
        acc0[3] += e0 * __uint_as_float(u0.y & 0xffff0000u);
        acc0[4] += e0 * __uint_as_float(u0.z << 16);
        acc0[5] += e0 * __uint_as_float(u0.z & 0xffff0000u);
        acc0[6] += e0 * __uint_as_float(u0.w << 16);
        acc0[7] += e0 * __uint_as_float(u0.w & 0xffff0000u);
        acc1[0] += e1 * __uint_as_float(u1.x << 16);
        acc1[1] += e1 * __uint_as_float(u1.x & 0xffff0000u);
        acc1[2] += e1 * __uint_as_float(u1.y << 16);
        acc1[3] += e1 * __uint_as_float(u1.y & 0xffff0000u);
        acc1[4] += e1 * __uint_as_float(u1.z << 16);
        acc1[5] += e1 * __uint_as_float(u1.z & 0xffff0000u);
        acc1[6] += e1 * __uint_as_float(u1.w << 16);
        acc1[7] += e1 * __uint_as_float(u1.w & 0xffff0000u);
        s = sn;
    }

    float d0 = __shfl(denom, g);
    float d1 = __shfl(denom, 4 + g);
    float r0 = 1.f / (d0 + 1e-16f);
    float r1 = 1.f / (d1 + 1e-16f);
    float sum[8];
#pragma unroll
    for (int i = 0; i < 8; i++) sum[i] = acc0[i] * r0 + acc1[i] * r1;
#pragma unroll
    for (int i = 0; i < 8; i++) {
        sum[i] += __shfl_xor(sum[i], 16);
        sum[i] += __shfl_xor(sum[i], 32);
    }

    if (lane < 16) {
        int c = 8 * lane;
        float o[8];
#pragma unroll
        for (int t = 0; t < 8; t++) {
            float m = sum[t] * 0.125f + bl[c + t];       // mean heads + bias
            float gg = gam[c + t] * (m * BN_INV) + bet[c + t];  // BN eval
            float z = 0.9f * gg + 0.1f * hprev[(size_t)n * 128 + c + t];
            o[t] = eluf(z);
        }
        *(float4*)(hnext + (size_t)n * 128 + c)     = make_float4(o[0], o[1], o[2], o[3]);
        *(float4*)(hnext + (size_t)n * 128 + c + 4) = make_float4(o[4], o[5], o[6], o[7]);
    }
}

// ---------------------------------------------------------------------------
// Classifier head: out = elu(h@W1+b1) @ W2 + b2, one wave per node.
// ---------------------------------------------------------------------------
__global__ __launch_bounds__(256) void k_classifier(const float* __restrict__ h,
                                                    const float* __restrict__ W1,
                                                    const float* __restrict__ b1,
                                                    const float* __restrict__ W2,
                                                    const float* __restrict__ b2,
                                                    float* __restrict__ out) {
    __shared__ float sW1[128 * 64];
    __shared__ float sW2[128];
    __shared__ float sb1[64];
    __shared__ float sb2[2];
    for (int i = threadIdx.x; i < 2048; i += 256)
        *(float4*)&sW1[i * 4] = *(const float4*)(W1 + i * 4);
    if (threadIdx.x < 64) sb1[threadIdx.x] = b1[threadIdx.x];
    if (threadIdx.x < 128) sW2[threadIdx.x] = W2[threadIdx.x];
    if (threadIdx.x < 2) sb2[threadIdx.x] = b2[threadIdx.x];
    __syncthreads();
    int lane = threadIdx.x & 63;
    int n = blockIdx.x * 4 + (threadIdx.x >> 6);
    if (n >= N_NODES) return;
    float h0 = h[(size_t)n * 128 + lane];
    float h1 = h[(size_t)n * 128 + 64 + lane];
    float acc = sb1[lane];
#pragma unroll
    for (int c = 0; c < 64; c++) acc += __shfl(h0, c) * sW1[c * 64 + lane];
#pragma unroll
    for (int c = 0; c < 64; c++) acc += __shfl(h1, c) * sW1[(64 + c) * 64 + lane];
    acc = eluf(acc);
    float p0 = acc * sW2[lane * 2 + 0];
    float p1 = acc * sW2[lane * 2 + 1];
#pragma unroll
    for (int m = 1; m < 64; m <<= 1) {
        p0 += __shfl_xor(p0, m);
        p1 += __shfl_xor(p1, m);
    }
    if (lane == 0) {
        out[(size_t)n * 2 + 0] = p0 + sb2[0];
        out[(size_t)n * 2 + 1] = p1 + sb2[1];
    }
}

// ---------------------------------------------------------------------------
extern "C" void kernel_launch(void* const* d_in, const int* in_sizes, int n_in,
                              void* d_out, int out_size, void* d_ws, size_t ws_size,
                              hipStream_t stream) {
    const float* x       = (const float*)d_in[0];
    const int* ei        = (const int*)d_in[1];   // int32 per harness convention
    const float* Wp      = (const float*)d_in[2];
    const float* bp      = (const float*)d_in[3];
    const float* Wl      = (const float*)d_in[4];
    const float* atts    = (const float*)d_in[5];
    const float* attd    = (const float*)d_in[6];
    const float* bl      = (const float*)d_in[7];
    const float* gam     = (const float*)d_in[8];
    const float* bet     = (const float*)d_in[9];
    const float* W1      = (const float*)d_in[10];
    const float* b1      = (const float*)d_in[11];
    const float* W2      = (const float*)d_in[12];
    const float* b2      = (const float*)d_in[13];
    float* out = (float*)d_out;

    char* w = (char*)d_ws;
    auto carve = [&](size_t bytes) -> void* {
        void* p = (void*)w;
        w += (bytes + 255) & ~(size_t)255;
        return p;
    };
    int* deg        = (int*)carve((size_t)N_NODES * 4);
    int* rowptr     = (int*)carve((size_t)(N_NODES + 1) * 4);
    int* cursor     = (int*)carve((size_t)N_NODES * 4);
    int* csr        = (int*)carve((size_t)(N_EDGES + N_NODES) * 4);
    float* as_      = (float*)carve((size_t)N_NODES * 8 * 4);
    float* ad_      = (float*)carve((size_t)N_NODES * 8 * 4);
    ushort16* xl    = (ushort16*)carve((size_t)N_NODES * 1024 * 2);  // bf16
    float* hA       = (float*)carve((size_t)N_NODES * 128 * 4);
    float* hB       = (float*)carve((size_t)N_NODES * 128 * 4);

    hipMemsetAsync(deg, 0, (size_t)N_NODES * 4, stream);
    k_deg<<<(N_EDGES + 255) / 256, 256, 0, stream>>>(ei, deg);
    k_scan<<<1, 1024, 0, stream>>>(deg, rowptr, cursor);
    k_scatter<<<(N_EDGES + N_NODES + 255) / 256, 256, 0, stream>>>(ei, cursor, csr);

    // h = elu(x @ Wp + bp)  (fp32)
    k_gemm<1, 0><<<dim3(2, 157), 256, 0, stream>>>(x, Wp, bp, hA, N_NODES, 128, 512);

    float* hc = hA;
    float* hn = hB;
    for (int l = 0; l < NLAYER; l++) {
        // xl = hc @ Wl[l]  (bf16 output)
        k_gemm<0, 1><<<dim3(16, 157), 256, 0, stream>>>(hc, Wl + (size_t)l * 128 * 1024, nullptr,
                                                        xl, N_NODES, 1024, 128);
        k_alphas<<<2500, 256, 0, stream>>>(xl, atts + l * 1024, attd + l * 1024, as_, ad_);
        k_aggregate<<<2500, 256, 0, stream>>>(rowptr, csr, as_, ad_, xl, hc, bl + l * 128,
                                              gam + l * 128, bet + l * 128, hn);
        float* tmp = hc; hc = hn; hn = tmp;
    }
    k_classifier<<<2500, 256, 0, stream>>>(hc, W1, b1, W2, b2, out);
}

// Round 8
// 504.302 us; speedup vs baseline: 1.5129x; 1.1602x over previous
//
#include <hip/hip_runtime.h>
#include <cstdint>
#include <cstddef>

#define N_NODES 10000
#define N_EDGES 160000
#define DIM_IN  512
#define HIDDIM  128
#define NHEAD   8
#define NLAYER  4

typedef unsigned int   uint32;
typedef unsigned short ushort16;
typedef __attribute__((ext_vector_type(8))) short bf16x8;
typedef __attribute__((ext_vector_type(4))) float f32x4;

static __device__ __forceinline__ float eluf(float v)  { return v > 0.f ? v : expm1f(v); }
static __device__ __forceinline__ float lrelu(float v) { return v >= 0.f ? v : 0.2f * v; }
static __device__ __forceinline__ ushort16 f2bf(float f) {  // RNE fp32->bf16
    uint32 u = __float_as_uint(f);
    u += 0x7fffu + ((u >> 16) & 1u);
    return (ushort16)(u >> 16);
}
static __device__ __forceinline__ float blo(uint32 u) { return __uint_as_float(u << 16); }
static __device__ __forceinline__ float bhi(uint32 u) { return __uint_as_float(u & 0xffff0000u); }

#define BN_INV 0.9999950000374997f  /* 1/sqrt(1+1e-5) */

// ---------------------------------------------------------------------------
// CSR build
// ---------------------------------------------------------------------------
__global__ void k_deg(const int* __restrict__ ei, int* __restrict__ deg) {
    int t = blockIdx.x * 256 + threadIdx.x;
    if (t < N_EDGES) atomicAdd(&deg[ei[N_EDGES + t]], 1);
}

__global__ __launch_bounds__(1024) void k_scan(const int* __restrict__ deg,
                                               int* __restrict__ rowptr,
                                               int* __restrict__ cursor) {
    __shared__ int sd[1024];
    __shared__ int carry;
    int tid = threadIdx.x;
    if (tid == 0) { carry = 0; rowptr[0] = 0; }
    __syncthreads();
    for (int base = 0; base < N_NODES; base += 1024) {
        int i = base + tid;
        int v = (i < N_NODES) ? (deg[i] + 1) : 0;  // +1 = self loop
        sd[tid] = v;
        __syncthreads();
        for (int ofs = 1; ofs < 1024; ofs <<= 1) {
            int t = (tid >= ofs) ? sd[tid - ofs] : 0;
            __syncthreads();
            sd[tid] += t;
            __syncthreads();
        }
        int inc = sd[tid] + carry;
        if (i < N_NODES) { rowptr[i + 1] = inc; cursor[i] = inc - v; }
        __syncthreads();
        if (tid == 1023) carry = inc;
        __syncthreads();
    }
}

__global__ void k_scatter(const int* __restrict__ ei, int* __restrict__ cursor,
                          int* __restrict__ csr) {
    int t = blockIdx.x * 256 + threadIdx.x;
    if (t < N_EDGES) {
        int s = ei[t];
        int d = ei[N_EDGES + t];
        int p = atomicAdd(&cursor[d], 1);
        csr[p] = s;
    } else if (t < N_EDGES + N_NODES) {
        int n = t - N_EDGES;
        int p = atomicAdd(&cursor[n], 1);
        csr[p] = n;  // self loop
    }
}

// ---------------------------------------------------------------------------
// bf16-MFMA GEMM: C[M,Nn] = A[M,K]@B[K,Nn], A/B fp32 in global, converted to
// bf16 during LDS staging. BM=BN=64, 256 thr (4 waves), wave w owns rows
// w*16..w*16+15 x all 64 cols (4 accs). K processed in 128-chunks.
// XOR swizzle byte^=(row&7)<<4 makes stride-256B fragment reads conflict-free.
// ACT=1: elu(.+bias) fp32 out. OUTBF=1: bf16 out.
// ---------------------------------------------------------------------------
template <int ACT, int OUTBF>
__global__ __launch_bounds__(256) void k_gemm_mfma(const float* __restrict__ A,
                                                   const float* __restrict__ B,
                                                   const float* __restrict__ bias,
                                                   void* __restrict__ Cv,
                                                   int M, int Nn, int K) {
    __shared__ unsigned short AsU[64 * 128];
    __shared__ unsigned short BsU[64 * 128];
    char* AsB = (char*)AsU;
    char* BsB = (char*)BsU;
    const int tid = threadIdx.x;
    const int lane = tid & 63;
    const int wv = tid >> 6;
    const int row0 = blockIdx.y * 64, col0 = blockIdx.x * 64;
    const int r = lane & 15, q = lane >> 4;

    f32x4 acc[4];
#pragma unroll
    for (int i = 0; i < 4; i++) acc[i] = (f32x4){0.f, 0.f, 0.f, 0.f};

    for (int k0 = 0; k0 < K; k0 += 128) {
        __syncthreads();
        // stage A: rows row0..row0+63, k k0..k0+127 (fp32 -> bf16, swizzled)
#pragma unroll
        for (int it = 0; it < 8; it++) {
            int gq = tid + it * 256;       // 0..2047
            int row = gq >> 5;             // 0..63
            int k4 = (gq & 31) * 4;        // 0,4,..,124
            int gr = row0 + row;
            float4 v = make_float4(0.f, 0.f, 0.f, 0.f);
            if (gr < M) v = *(const float4*)(A + (size_t)gr * K + k0 + k4);
            ushort4 o;
            o.x = f2bf(v.x); o.y = f2bf(v.y); o.z = f2bf(v.z); o.w = f2bf(v.w);
            int byte = (row * 256 + k4 * 2) ^ ((row & 7) << 4);
            *(ushort4*)(AsB + byte) = o;
        }
        // stage B transposed: Bs[col][k] (col-major so fragments are contiguous)
#pragma unroll
        for (int it = 0; it < 8; it++) {
            int gq = tid + it * 256;       // 0..2047
            int kk = gq >> 4;              // 0..127
            int c4 = (gq & 15) * 4;        // 0,4,..,60
            float4 v = *(const float4*)(B + (size_t)(k0 + kk) * Nn + col0 + c4);
            float vv[4] = {v.x, v.y, v.z, v.w};
#pragma unroll
            for (int c = 0; c < 4; c++) {
                int col = c4 + c;
                int byte = (col * 256 + kk * 2) ^ ((col & 7) << 4);
                *(unsigned short*)(BsB + byte) = f2bf(vv[c]);
            }
        }
        __syncthreads();
        // compute: 4 K-steps of 32
#pragma unroll
        for (int ks = 0; ks < 4; ks++) {
            int kb = (ks * 32 + q * 8) * 2;       // byte offset of 8 bf16
            int arow = wv * 16 + r;
            bf16x8 af = *(bf16x8*)(AsB + ((arow * 256 + kb) ^ ((arow & 7) << 4)));
#pragma unroll
            for (int nb = 0; nb < 4; nb++) {
                int col = nb * 16 + r;
                bf16x8 bfr = *(bf16x8*)(BsB + ((col * 256 + kb) ^ ((col & 7) << 4)));
                acc[nb] = __builtin_amdgcn_mfma_f32_16x16x32_bf16(af, bfr, acc[nb], 0, 0, 0);
            }
        }
    }
    // epilogue: D lane mapping col=lane&15, row=(lane>>4)*4+reg
#pragma unroll
    for (int nb = 0; nb < 4; nb++) {
        int col = col0 + nb * 16 + r;
#pragma unroll
        for (int j = 0; j < 4; j++) {
            int row = row0 + wv * 16 + q * 4 + j;
            if (row < M) {
                float v = acc[nb][j];
                if (ACT) { v += bias[col]; v = eluf(v); }
                if (OUTBF) ((unsigned short*)Cv)[(size_t)row * Nn + col] = f2bf(v);
                else       ((float*)Cv)[(size_t)row * Nn + col] = v;
            }
        }
    }
}

// ---------------------------------------------------------------------------
// alpha_s[n,h] = sum_c xl[n,h,c]*att_src[h,c] (xl bf16). One wave/node.
// ---------------------------------------------------------------------------
__global__ __launch_bounds__(256) void k_alphas(const ushort16* __restrict__ xl,
                                                const float* __restrict__ atts,
                                                const float* __restrict__ attd,
                                                float* __restrict__ as_,
                                                float* __restrict__ ad_) {
    int lane = threadIdx.x & 63;
    int n = blockIdx.x * 4 + (threadIdx.x >> 6);
    if (n >= N_NODES) return;
    int g = lane >> 4;          // 0..3
    int c8 = 8 * (lane & 15);   // channel base
    const uint4* xp = (const uint4*)(xl + (size_t)n * 1024);
    float ss[2], sd[2];
#pragma unroll
    for (int j = 0; j < 2; j++) {
        int head = 4 * j + g;
        uint4 u = xp[j * 64 + lane];
        const float4* ap = (const float4*)(atts + head * 128 + c8);
        const float4* bp = (const float4*)(attd + head * 128 + c8);
        float4 a0 = ap[0], a1 = ap[1];
        float4 b0 = bp[0], b1 = bp[1];
        float x0 = blo(u.x), x1 = bhi(u.x), x2 = blo(u.y), x3 = bhi(u.y);
        float x4 = blo(u.z), x5 = bhi(u.z), x6 = blo(u.w), x7 = bhi(u.w);
        ss[j] = x0 * a0.x + x1 * a0.y + x2 * a0.z + x3 * a0.w +
                x4 * a1.x + x5 * a1.y + x6 * a1.z + x7 * a1.w;
        sd[j] = x0 * b0.x + x1 * b0.y + x2 * b0.z + x3 * b0.w +
                x4 * b1.x + x5 * b1.y + x6 * b1.z + x7 * b1.w;
    }
#pragma unroll
    for (int m = 1; m < 16; m <<= 1) {
#pragma unroll
        for (int j = 0; j < 2; j++) {
            ss[j] += __shfl_xor(ss[j], m);
            sd[j] += __shfl_xor(sd[j], m);
        }
    }
    if ((lane & 15) == 0) {
        as_[n * 8 + g]     = ss[0];
        as_[n * 8 + 4 + g] = ss[1];
        ad_[n * 8 + g]     = sd[0];
        ad_[n * 8 + 4 + g] = sd[1];
    }
}

// ---------------------------------------------------------------------------
// Aggregation, 2-edge unrolled for MLP (4x 16B gathers in flight).
// One wave/node. Lane l: denom for head l&7; payload heads g and 4+g
// (g=l>>4), channels 8*(l&15)..+7. No max-shift (|e| small; ratio invariant).
// ---------------------------------------------------------------------------
__global__ __launch_bounds__(256) void k_aggregate(const int* __restrict__ rowptr,
                                                   const int* __restrict__ csr,
                                                   const float* __restrict__ as_,
                                                   const float* __restrict__ ad_,
                                                   const ushort16* __restrict__ xl,
                                                   const float* __restrict__ hprev,
                                                   const float* __restrict__ bl,
                                                   const float* __restrict__ gam,
                                                   const float* __restrict__ bet,
                                                   float* __restrict__ hnext) {
    int lane = threadIdx.x & 63;
    int n = blockIdx.x * 4 + (threadIdx.x >> 6);
    if (n >= N_NODES) return;
    int h8 = lane & 7;
    int g = lane >> 4;
    float adh = ad_[n * 8 + h8];
    int start = rowptr[n], end = rowptr[n + 1];

    float acc0[8] = {}, acc1[8] = {};
    float denom = 0.f;
    int e = start;
    int s0 = csr[e];                              // deg >= 1 (self-loop)
    int s1 = (e + 1 < end) ? csr[e + 1] : 0;
    for (; e + 1 < end; e += 2) {
        int s2 = (e + 2 < end) ? csr[e + 2] : 0;  // prefetch
        int s3 = (e + 3 < end) ? csr[e + 3] : 0;
        float as0 = as_[s0 * 8 + h8];
        float as1 = as_[s1 * 8 + h8];
        const uint4* xp0 = (const uint4*)(xl + (size_t)s0 * 1024);
        const uint4* xp1 = (const uint4*)(xl + (size_t)s1 * 1024);
        uint4 u0a = xp0[lane], u1a = xp0[64 + lane];
        uint4 u0b = xp1[lane], u1b = xp1[64 + lane];
        float ee0 = __expf(lrelu(as0 + adh));
        float ee1 = __expf(lrelu(as1 + adh));
        denom += ee0 + ee1;
        float e0a = __shfl(ee0, g), e1a = __shfl(ee0, 4 + g);
        float e0b = __shfl(ee1, g), e1b = __shfl(ee1, 4 + g);
        acc0[0] += e0a * blo(u0a.x); acc0[1] += e0a * bhi(u0a.x);
        acc0[2] += e0a * blo(u0a.y); acc0[3] += e0a * bhi(u0a.y);
        acc0[4] += e0a * blo(u0a.z); acc0[5] += e0a * bhi(u0a.z);
        acc0[6] += e0a * blo(u0a.w); acc0[7] += e0a * bhi(u0a.w);
        acc1[0] += e1a * blo(u1a.x); acc1[1] += e1a * bhi(u1a.x);
        acc1[2] += e1a * blo(u1a.y); acc1[3] += e1a * bhi(u1a.y);
        acc1[4] += e1a * blo(u1a.z); acc1[5] += e1a * bhi(u1a.z);
        acc1[6] += e1a * blo(u1a.w); acc1[7] += e1a * bhi(u1a.w);
        acc0[0] += e0b * blo(u0b.x); acc0[1] += e0b * bhi(u0b.x);
        acc0[2] += e0b * blo(u0b.y); acc0[3] += e0b * bhi(u0b.y);
        acc0[4] += e0b * blo(u0b.z); acc0[5] += e0b * bhi(u0b.z);
        acc0[6] += e0b * blo(u0b.w); acc0[7] += e0b * bhi(u0b.w);
        acc1[0] += e1b * blo(u1b.x); acc1[1] += e1b * bhi(u1b.x);
        acc1[2] += e1b * blo(u1b.y); acc1[3] += e1b * bhi(u1b.y);
        acc1[4] += e1b * blo(u1b.z); acc1[5] += e1b * bhi(u1b.z);
        acc1[6] += e1b * blo(u1b.w); acc1[7] += e1b * bhi(u1b.w);
        s0 = s2; s1 = s3;
    }
    if (e < end) {  // odd tail
        float as0 = as_[s0 * 8 + h8];
        const uint4* xp0 = (const uint4*)(xl + (size_t)s0 * 1024);
        uint4 u0a = xp0[lane], u1a = xp0[64 + lane];
        float ee0 = __expf(lrelu(as0 + adh));
        denom += ee0;
        float e0a = __shfl(ee0, g), e1a = __shfl(ee0, 4 + g);
        acc0[0] += e0a * blo(u0a.x); acc0[1] += e0a * bhi(u0a.x);
        acc0[2] += e0a * blo(u0a.y); acc0[3] += e0a * bhi(u0a.y);
        acc0[4] += e0a * blo(u0a.z); acc0[5] += e0a * bhi(u0a.z);
        acc0[6] += e0a * blo(u0a.w); acc0[7] += e0a * bhi(u0a.w);
        acc1[0] += e1a * blo(u1a.x); acc1[1] += e1a * bhi(u1a.x);
        acc1[2] += e1a * blo(u1a.y); acc1[3] += e1a * bhi(u1a.y);
        acc1[4] += e1a * blo(u1a.z); acc1[5] += e1a * bhi(u1a.z);
        acc1[6] += e1a * blo(u1a.w); acc1[7] += e1a * bhi(u1a.w);
    }

    float d0 = __shfl(denom, g);
    float d1 = __shfl(denom, 4 + g);
    float r0 = 1.f / (d0 + 1e-16f);
    float r1 = 1.f / (d1 + 1e-16f);
    float sum[8];
#pragma unroll
    for (int i = 0; i < 8; i++) sum[i] = acc0[i] * r0 + acc1[i] * r1;
#pragma unroll
    for (int i = 0; i < 8; i++) {
        sum[i] += __shfl_xor(sum[i], 16);
        sum[i] += __shfl_xor(sum[i], 32);
    }

    if (lane < 16) {
        int c = 8 * lane;
        float o[8];
#pragma unroll
        for (int t = 0; t < 8; t++) {
            float m = sum[t] * 0.125f + bl[c + t];              // mean heads + bias
            float gg = gam[c + t] * (m * BN_INV) + bet[c + t];  // BN eval
            float z = 0.9f * gg + 0.1f * hprev[(size_t)n * 128 + c + t];
            o[t] = eluf(z);
        }
        *(float4*)(hnext + (size_t)n * 128 + c)     = make_float4(o[0], o[1], o[2], o[3]);
        *(float4*)(hnext + (size_t)n * 128 + c + 4) = make_float4(o[4], o[5], o[6], o[7]);
    }
}

// ---------------------------------------------------------------------------
// Classifier head: out = elu(h@W1+b1) @ W2 + b2, one wave per node.
// ---------------------------------------------------------------------------
__global__ __launch_bounds__(256) void k_classifier(const float* __restrict__ h,
                                                    const float* __restrict__ W1,
                                                    const float* __restrict__ b1,
                                                    const float* __restrict__ W2,
                                                    const float* __restrict__ b2,
                                                    float* __restrict__ out) {
    __shared__ float sW1[128 * 64];
    __shared__ float sW2[128];
    __shared__ float sb1[64];
    __shared__ float sb2[2];
    for (int i = threadIdx.x; i < 2048; i += 256)
        *(float4*)&sW1[i * 4] = *(const float4*)(W1 + i * 4);
    if (threadIdx.x < 64) sb1[threadIdx.x] = b1[threadIdx.x];
    if (threadIdx.x < 128) sW2[threadIdx.x] = W2[threadIdx.x];
    if (threadIdx.x < 2) sb2[threadIdx.x] = b2[threadIdx.x];
    __syncthreads();
    int lane = threadIdx.x & 63;
    int n = blockIdx.x * 4 + (threadIdx.x >> 6);
    if (n >= N_NODES) return;
    float h0 = h[(size_t)n * 128 + lane];
    float h1 = h[(size_t)n * 128 + 64 + lane];
    float acc = sb1[lane];
#pragma unroll
    for (int c = 0; c < 64; c++) acc += __shfl(h0, c) * sW1[c * 64 + lane];
#pragma unroll
    for (int c = 0; c < 64; c++) acc += __shfl(h1, c) * sW1[(64 + c) * 64 + lane];
    acc = eluf(acc);
    float p0 = acc * sW2[lane * 2 + 0];
    float p1 = acc * sW2[lane * 2 + 1];
#pragma unroll
    for (int m = 1; m < 64; m <<= 1) {
        p0 += __shfl_xor(p0, m);
        p1 += __shfl_xor(p1, m);
    }
    if (lane == 0) {
        out[(size_t)n * 2 + 0] = p0 + sb2[0];
        out[(size_t)n * 2 + 1] = p1 + sb2[1];
    }
}

// ---------------------------------------------------------------------------
extern "C" void kernel_launch(void* const* d_in, const int* in_sizes, int n_in,
                              void* d_out, int out_size, void* d_ws, size_t ws_size,
                              hipStream_t stream) {
    const float* x       = (const float*)d_in[0];
    const int* ei        = (const int*)d_in[1];   // int32 per harness convention
    const float* Wp      = (const float*)d_in[2];
    const float* bp      = (const float*)d_in[3];
    const float* Wl      = (const float*)d_in[4];
    const float* atts    = (const float*)d_in[5];
    const float* attd    = (const float*)d_in[6];
    const float* bl      = (const float*)d_in[7];
    const float* gam     = (const float*)d_in[8];
    const float* bet     = (const float*)d_in[9];
    const float* W1      = (const float*)d_in[10];
    const float* b1      = (const float*)d_in[11];
    const float* W2      = (const float*)d_in[12];
    const float* b2      = (const float*)d_in[13];
    float* out = (float*)d_out;

    char* w = (char*)d_ws;
    auto carve = [&](size_t bytes) -> void* {
        void* p = (void*)w;
        w += (bytes + 255) & ~(size_t)255;
        return p;
    };
    int* deg        = (int*)carve((size_t)N_NODES * 4);
    int* rowptr     = (int*)carve((size_t)(N_NODES + 1) * 4);
    int* cursor     = (int*)carve((size_t)N_NODES * 4);
    int* csr        = (int*)carve((size_t)(N_EDGES + N_NODES) * 4);
    float* as_      = (float*)carve((size_t)N_NODES * 8 * 4);
    float* ad_      = (float*)carve((size_t)N_NODES * 8 * 4);
    ushort16* xl    = (ushort16*)carve((size_t)N_NODES * 1024 * 2);  // bf16
    float* hA       = (float*)carve((size_t)N_NODES * 128 * 4);
    float* hB       = (float*)carve((size_t)N_NODES * 128 * 4);

    hipMemsetAsync(deg, 0, (size_t)N_NODES * 4, stream);
    k_deg<<<(N_EDGES + 255) / 256, 256, 0, stream>>>(ei, deg);
    k_scan<<<1, 1024, 0, stream>>>(deg, rowptr, cursor);
    k_scatter<<<(N_EDGES + N_NODES + 255) / 256, 256, 0, stream>>>(ei, cursor, csr);

    // h = elu(x @ Wp + bp)  (bf16-MFMA, fp32 out)
    k_gemm_mfma<1, 0><<<dim3(2, 157), 256, 0, stream>>>(x, Wp, bp, hA, N_NODES, 128, 512);

    float* hc = hA;
    float* hn = hB;
    for (int l = 0; l < NLAYER; l++) {
        // xl = hc @ Wl[l]  (bf16-MFMA, bf16 out)
        k_gemm_mfma<0, 1><<<dim3(16, 157), 256, 0, stream>>>(hc, Wl + (size_t)l * 128 * 1024,
                                                             nullptr, xl, N_NODES, 1024, 128);
        k_alphas<<<2500, 256, 0, stream>>>(xl, atts + l * 1024, attd + l * 1024, as_, ad_);
        k_aggregate<<<2500, 256, 0, stream>>>(rowptr, csr, as_, ad_, xl, hc, bl + l * 128,
                                              gam + l * 128, bet + l * 128, hn);
        float* tmp = hc; hc = hn; hn = tmp;
    }
    k_classifier<<<2500, 256, 0, stream>>>(hc, W1, b1, W2, b2, out);
}